// Round 4
// baseline (153.790 us; speedup 1.0000x reference)
//
#include <hip/hip_runtime.h>
#include <cmath>

#define H     256
#define H3    768
#define L     32
#define STEPS 20
#define VOUT  74
#define NWG   16
#define HW    16            // h rows per WG
#define ROWS  48            // gh rows per WG (3 gates x 16)
#define NITEMS (L + VOUT)   // 106

// ---- workspace layout (32-bit word offsets) ----
// WS_HX: [2][256] exchange entries, each padded to 64B (16 floats);
//        packed (h_value<<32 | step_tag) u64 lives at slot 0 of each entry.
#define WS_HX    0                       // 8192 floats (32 KB)
#define WS_EGI   8192                    // float [32][768]
#define WS_DGI   (8192 + L * H3)         // float [74][768] -> 32768

__device__ __forceinline__ float sigmoidf_(float x) {
    return 1.0f / (1.0f + expf(-x));
}

// global gh-row for local row lr (0..47) of workgroup w:
// lr 0..15 -> r-gate rows j, 16..31 -> z rows H+j, 32..47 -> n rows 2H+j
__device__ __forceinline__ int growf(int w, int lr) {
    int j = w * HW + (lr & 15);
    return (lr < 16) ? j : (lr < 32 ? H + j : 2 * H + j);
}

// Prep: zero the padded exchange buffer; precompute all input-side gate
// projections (encoder steps + all 74 decoder candidate tokens).
__global__ void prep(const int*   __restrict__ enc_input,
                     const float* __restrict__ enc_emb,
                     const float* __restrict__ encWih,
                     const float* __restrict__ enc_bih,
                     const float* __restrict__ dec_emb,
                     const float* __restrict__ decWih,
                     const float* __restrict__ dec_bih,
                     float* __restrict__ ws) {
    if (blockIdx.x == 0) {
        // tags -> 0 == h^0 (value bits 0.0f) for parity-0; parity-1 tags 0 != 1
        for (int k = threadIdx.x; k < 8192; k += 256) ((int*)ws)[k] = 0;
    }
    int wid  = blockIdx.x * 4 + (threadIdx.x >> 6);
    int lane = threadIdx.x & 63;
    if (wid >= NITEMS * H3) return;
    int item = wid / H3;
    int j    = wid - item * H3;

    const float* x; const float* W; const float* b; float* out;
    if (item < L) {
        x = enc_emb + enc_input[item] * H;  W = encWih + j * H;
        b = enc_bih;                        out = ws + WS_EGI + item * H3 + j;
    } else {
        int v = item - L;
        x = dec_emb + v * H;                W = decWih + j * H;
        b = dec_bih;                        out = ws + WS_DGI + v * H3 + j;
    }
    float4 w  = ((const float4*)W)[lane];
    float4 xv = ((const float4*)x)[lane];
    float s = fmaf(w.x, xv.x, fmaf(w.y, xv.y, fmaf(w.z, xv.z, w.w * xv.w)));
    #pragma unroll
    for (int m = 1; m < 64; m <<= 1) s += __shfl_xor(s, m);
    if (lane == 0) *out = s + b[j];
}

// Sequential phase: 16 WGs. Whh + fc_W in registers, gi slices in LDS,
// h exchanged via 64B-padded tagged 8-byte agent-scope atomics.
__global__ __launch_bounds__(256, 1) void gru_seq(
        const float* __restrict__ enc_Whh, const float* __restrict__ enc_bhh,
        const float* __restrict__ dec_Whh, const float* __restrict__ dec_bhh,
        const float* __restrict__ fc_W,    const float* __restrict__ fc_b,
        float* __restrict__ ws, int* __restrict__ out) {
    __shared__ __align__(16) float hl[1040];   // 4 bank-shifted copies (stride 260)
    __shared__ float fb[VOUT];
    __shared__ float gh_l[ROWS];
    __shared__ float egi_l[L * ROWS];          // [32][48] this WG's enc gi slice
    __shared__ float dgi_l[VOUT * ROWS];       // [74][48] gi slice per candidate tok
    __shared__ float log_l[VOUT];
    __shared__ int   s_tok, s_done;

    const int t = threadIdx.x;
    const int w = blockIdx.x;
    unsigned long long* hx = (unsigned long long*)(ws + WS_HX);

    // ---- one-time staging ----
    if (t == 0) { s_done = 0; s_tok = 2; }      // BOS=2
    if (w == 0 && t < STEPS) out[t] = 0;
    if (t < VOUT) fb[t] = fc_b[t];
    for (int idx = t; idx < L * ROWS; idx += 256) {
        int item = idx / ROWS, lr = idx - item * ROWS;
        egi_l[idx] = ws[WS_EGI + item * H3 + growf(w, lr)];
    }
    for (int idx = t; idx < VOUT * ROWS; idx += 256) {
        int item = idx / ROWS, lr = idx - item * ROWS;
        dgi_l[idx] = ws[WS_DGI + item * H3 + growf(w, lr)];
    }

    // Whh slices (matvec workers t in [64,256): m = t-64, 4 threads per row)
    const int m  = t - 64;
    const int p  = t & 3;                 // k-chunk (== m&3 since 64%4==0)
    const int lr = (t >= 64) ? (m >> 2) : 0;
    const int g  = growf(w, lr);
    float4 wE[16], wD[16];
    float bhhE = 0.f, bhhD = 0.f;
    if (t >= 64) {
        const float* eb = enc_Whh + g * H + p * 64;
        const float* db = dec_Whh + g * H + p * 64;
        #pragma unroll
        for (int i = 0; i < 16; ++i) {
            wE[i] = *(const float4*)(eb + 4 * i);
            wD[i] = *(const float4*)(db + 4 * i);
        }
        if (p == 0) { bhhE = enc_bhh[g]; bhhD = dec_bhh[g]; }
    }

    // fc_W slices in registers: primary = row t>>2 (0..63), chunk t&3;
    // secondary (t<40) = row 64+(t>>2), chunk t&3.  74*4 = 296 = 256 + 40 tasks.
    const int rF = t >> 2;
    float4 wF[16], wF2[16];
    {
        const float* fp = fc_W + rF * H + p * 64;
        #pragma unroll
        for (int i = 0; i < 16; ++i) wF[i] = *(const float4*)(fp + 4 * i);
        if (t < 40) {
            const float* fp2 = fc_W + (64 + rF) * H + p * 64;
            #pragma unroll
            for (int i = 0; i < 16; ++i) wF2[i] = *(const float4*)(fp2 + 4 * i);
        }
    }

    int tok = 2;  // BOS
    for (int s = 0; s <= L + STEPS; ++s) {      // 0..52
        // ---- wait for h^(s): thread t polls its own 64B-padded entry ----
        {
            const unsigned long long* src = hx + ((unsigned)((s & 1) * H + t)) * 8;
            unsigned long long u;
            do {
                u = __hip_atomic_load(src, __ATOMIC_RELAXED,
                                      __HIP_MEMORY_SCOPE_AGENT);
            } while ((unsigned)u != (unsigned)s);
            float hv = __uint_as_float((unsigned)(u >> 32));
            hl[t] = hv; hl[260 + t] = hv; hl[520 + t] = hv; hl[780 + t] = hv;
        }
        __syncthreads();

        const bool dec_out = (s >= L + 1);
        if (dec_out) {
            // ---- logits from registers (all 256 threads, conflict-free hl) ----
            const float* hb = hl + p * 324;
            float a = 0.f;
            #pragma unroll
            for (int i = 0; i < 16; ++i) {
                float4 h4 = *(const float4*)(hb + 4 * i);
                a = fmaf(wF[i].x, h4.x, fmaf(wF[i].y, h4.y,
                      fmaf(wF[i].z, h4.z, fmaf(wF[i].w, h4.w, a))));
            }
            a += __shfl_xor(a, 1); a += __shfl_xor(a, 2);
            if (p == 0) log_l[rF] = a + fb[rF];
            if (t < 40) {
                float a2 = 0.f;
                #pragma unroll
                for (int i = 0; i < 16; ++i) {
                    float4 h4 = *(const float4*)(hb + 4 * i);
                    a2 = fmaf(wF2[i].x, h4.x, fmaf(wF2[i].y, h4.y,
                           fmaf(wF2[i].z, h4.z, fmaf(wF2[i].w, h4.w, a2))));
                }
                a2 += __shfl_xor(a2, 1); a2 += __shfl_xor(a2, 2);
                if (p == 0) log_l[64 + rF] = a2 + fb[64 + rF];
            }
            __syncthreads();
        }

        // ---- wave0: argmax  ||  waves1-3: GRU matvec (tok-independent) ----
        if (t < 64) {
            if (dec_out) {
                float v = log_l[t]; int bi = t;
                if (t < VOUT - 64) {
                    float v2 = log_l[64 + t];
                    if (v2 > v) { v = v2; bi = 64 + t; }
                }
                #pragma unroll
                for (int mm = 1; mm < 64; mm <<= 1) {
                    float ov = __shfl_xor(v, mm);
                    int   ob = __shfl_xor(bi, mm);
                    if (ov > v || (ov == v && ob < bi)) { v = ov; bi = ob; }
                }
                if (t == 0) {
                    bool eos = (bi == 3);                    // EOS=3
                    if (w == 0 && !eos) out[s - (L + 1)] = bi;
                    s_tok = bi;
                    if (eos) s_done = 1;
                }
            }
        } else {
            float acc = (s < L) ? bhhE : bhhD;
            const float* hb = hl + p * 324;      // copy p, k-offset p*64
            if (s < L) {
                #pragma unroll
                for (int i = 0; i < 16; ++i) {
                    float4 h4 = *(const float4*)(hb + 4 * i);
                    acc = fmaf(wE[i].x, h4.x, fmaf(wE[i].y, h4.y,
                          fmaf(wE[i].z, h4.z, fmaf(wE[i].w, h4.w, acc))));
                }
            } else {
                #pragma unroll
                for (int i = 0; i < 16; ++i) {
                    float4 h4 = *(const float4*)(hb + 4 * i);
                    acc = fmaf(wD[i].x, h4.x, fmaf(wD[i].y, h4.y,
                          fmaf(wD[i].z, h4.z, fmaf(wD[i].w, h4.w, acc))));
                }
            }
            acc += __shfl_xor(acc, 1);
            acc += __shfl_xor(acc, 2);
            if (p == 0) gh_l[m >> 2] = acc;
        }
        __syncthreads();

        if (dec_out) {
            tok = s_tok;
            if (s_done || s == L + STEPS) break;
        }

        // ---- gates -> h^(s+1) slice: ONE padded 8B tagged store ----
        if (t < HW) {
            const float* gi = (s < L) ? (egi_l + s * ROWS) : (dgi_l + tok * ROWS);
            float r = sigmoidf_(gi[t]      + gh_l[t]);
            float z = sigmoidf_(gi[16 + t] + gh_l[16 + t]);
            float n = tanhf    (gi[32 + t] + r * gh_l[32 + t]);
            float hn = (1.f - z) * n + z * hl[w * HW + t];
            unsigned long long pk =
                ((unsigned long long)__float_as_uint(hn) << 32) |
                (unsigned)(s + 1);
            __hip_atomic_store(hx + ((unsigned)(((s + 1) & 1) * H + w * HW + t)) * 8,
                               pk, __ATOMIC_RELAXED, __HIP_MEMORY_SCOPE_AGENT);
        }
        // no trailing barrier: cross-WG ordering rides on the tagged word;
        // intra-WG LDS hazards are covered by the per-iteration barriers.
    }
}

extern "C" void kernel_launch(void* const* d_in, const int* in_sizes, int n_in,
                              void* d_out, int out_size, void* d_ws, size_t ws_size,
                              hipStream_t stream) {
    const int*   enc_input = (const int*)  d_in[0];
    const float* enc_emb   = (const float*)d_in[1];
    const float* enc_Wih   = (const float*)d_in[2];
    const float* enc_Whh   = (const float*)d_in[3];
    const float* enc_bih   = (const float*)d_in[4];
    const float* enc_bhh   = (const float*)d_in[5];
    const float* dec_emb   = (const float*)d_in[6];
    const float* dec_Wih   = (const float*)d_in[7];
    const float* dec_Whh   = (const float*)d_in[8];
    const float* dec_bih   = (const float*)d_in[9];
    const float* dec_bhh   = (const float*)d_in[10];
    const float* fc_W      = (const float*)d_in[11];
    const float* fc_b      = (const float*)d_in[12];
    float* ws  = (float*)d_ws;
    int*  outp = (int*)d_out;

    hipLaunchKernelGGL(prep, dim3((NITEMS * H3 + 3) / 4), dim3(256), 0, stream,
                       enc_input, enc_emb, enc_Wih, enc_bih,
                       dec_emb, dec_Wih, dec_bih, ws);
    hipLaunchKernelGGL(gru_seq, dim3(NWG), dim3(256), 0, stream,
                       enc_Whh, enc_bhh, dec_Whh, dec_bhh, fc_W, fc_b,
                       ws, outp);
}

// Round 5
// 133.849 us; speedup vs baseline: 1.1490x; 1.1490x over previous
//
#include <hip/hip_runtime.h>
#include <cmath>

#define H     256
#define H3    768
#define L     32
#define STEPS 20
#define VOUT  74
#define NP    16            // participant WGs (elected, same XCD)
#define NB    128           // launched WGs (pigeonhole: some XCD gets >=16)
#define HW    16            // h rows per WG
#define ROWS  48            // gh rows per WG (3 gates x 16)
#define NITEMS (L + VOUT)   // 106

// ---- workspace layout (32-bit word offsets) ----
#define WS_CNT   0                        // int cnt[8] per-XCD arrival tickets
#define WS_WIN   8                        // int winner (-1 until elected)
#define WS_HX    16                       // u64 [2][256] packed (val<<32|tag)
#define WS_EGI   1040                     // float [NP][L][48]   blocked by consumer
#define WS_DGI   (1040 + NP * L * ROWS)   // float [NP][VOUT][48] -> 25616
// end: 25616 + 16*74*48 = 82448 words (~322 KB)

__device__ __forceinline__ float sigmoidf_(float x) {
    return 1.0f / (1.0f + expf(-x));
}

// global gh-row for local row lr (0..47) of role w:
// lr 0..15 -> r rows j, 16..31 -> z rows H+j, 32..47 -> n rows 2H+j
__device__ __forceinline__ int growf(int w, int lr) {
    int j = w * HW + (lr & 15);
    return (lr < 16) ? j : (lr < 32 ? H + j : 2 * H + j);
}

// Prep: reset election state + exchange tags; precompute all input-side gate
// projections into the consumer-blocked layout [role][item][48].
__global__ void prep(const int*   __restrict__ enc_input,
                     const float* __restrict__ enc_emb,
                     const float* __restrict__ encWih,
                     const float* __restrict__ enc_bih,
                     const float* __restrict__ dec_emb,
                     const float* __restrict__ decWih,
                     const float* __restrict__ dec_bih,
                     float* __restrict__ ws) {
    if (blockIdx.x == 0) {
        for (int k = threadIdx.x; k < 1040; k += 256) ((int*)ws)[k] = 0;
        if (threadIdx.x == 0) ((int*)ws)[WS_WIN] = -1;
    }
    int wid  = blockIdx.x * 4 + (threadIdx.x >> 6);
    int lane = threadIdx.x & 63;
    if (wid >= NITEMS * H3) return;
    int item = wid / H3;
    int j    = wid - item * H3;
    int wOwn = (j & 255) >> 4;                 // consumer role
    int lr   = (j >> 8) * 16 + (j & 15);       // local row within role

    const float* x; const float* W; const float* b; float* out;
    if (item < L) {
        x = enc_emb + enc_input[item] * H;  W = encWih + j * H;
        b = enc_bih;
        out = ws + WS_EGI + (wOwn * L + item) * ROWS + lr;
    } else {
        int v = item - L;
        x = dec_emb + v * H;                W = decWih + j * H;
        b = dec_bih;
        out = ws + WS_DGI + (wOwn * VOUT + v) * ROWS + lr;
    }
    float4 w  = ((const float4*)W)[lane];
    float4 xv = ((const float4*)x)[lane];
    float s = fmaf(w.x, xv.x, fmaf(w.y, xv.y, fmaf(w.z, xv.z, w.w * xv.w)));
    #pragma unroll
    for (int m = 1; m < 64; m <<= 1) s += __shfl_xor(s, m);
    if (lane == 0) *out = s + b[j];
}

// Sequential phase: 16 elected same-XCD WGs. Whh + fc_W in registers,
// gi slices in LDS, h exchanged via packed tagged 8B agent-scope atomics
// that should now be serviced by the shared XCD-local L2.
__global__ __launch_bounds__(256, 1) void gru_seq(
        const float* __restrict__ enc_Whh, const float* __restrict__ enc_bhh,
        const float* __restrict__ dec_Whh, const float* __restrict__ dec_bhh,
        const float* __restrict__ fc_W,    const float* __restrict__ fc_b,
        float* __restrict__ ws, int* __restrict__ out) {
    __shared__ __align__(16) float hl[1040];   // 4 bank-shifted copies (stride 260)
    __shared__ float fb[VOUT];
    __shared__ float gh_l[ROWS];
    __shared__ float egi_l[L * ROWS];          // [32][48]
    __shared__ float dgi_l[VOUT * ROWS];       // [74][48]
    __shared__ float log_l[VOUT];
    __shared__ int   s_tok, s_done, s_role;

    const int t = threadIdx.x;

    // ---- election: first XCD to collect NP workgroups wins ----
    if (t == 0) {
        int xcd;
        asm volatile("s_getreg_b32 %0, hwreg(HW_REG_XCC_ID)" : "=s"(xcd));
        xcd &= 7;
        int* cnt = (int*)ws + WS_CNT;
        int* win = (int*)ws + WS_WIN;
        int rank = __hip_atomic_fetch_add(&cnt[xcd], 1, __ATOMIC_RELAXED,
                                          __HIP_MEMORY_SCOPE_AGENT);
        if (rank == NP - 1) {
            int expect = -1;
            __hip_atomic_compare_exchange_strong(win, &expect, xcd,
                __ATOMIC_RELAXED, __ATOMIC_RELAXED, __HIP_MEMORY_SCOPE_AGENT);
        }
        int wv;
        while ((wv = __hip_atomic_load(win, __ATOMIC_RELAXED,
                                       __HIP_MEMORY_SCOPE_AGENT)) < 0)
            __builtin_amdgcn_s_sleep(2);
        s_role = (wv == xcd && rank < NP) ? rank : -1;
        s_done = 0; s_tok = 2;                  // BOS=2
    }
    __syncthreads();
    const int w = s_role;
    if (w < 0) return;                          // non-participant

    unsigned long long* hx = (unsigned long long*)((int*)ws + WS_HX);

    // ---- one-time staging (coalesced: blocked gi layout) ----
    if (w == 0 && t < STEPS) out[t] = 0;
    if (t < VOUT) fb[t] = fc_b[t];
    for (int idx = t; idx < L * ROWS; idx += 256)
        egi_l[idx] = ws[WS_EGI + w * (L * ROWS) + idx];
    for (int idx = t; idx < VOUT * ROWS; idx += 256)
        dgi_l[idx] = ws[WS_DGI + w * (VOUT * ROWS) + idx];

    // Whh slices (matvec workers t in [64,256): 4 threads per gh row)
    const int m  = t - 64;
    const int p  = t & 3;                 // k-chunk (64 floats each)
    const int lr = (t >= 64) ? (m >> 2) : 0;
    const int g  = growf(w, lr);
    float4 wE[16], wD[16];
    float bhhE = 0.f, bhhD = 0.f;
    if (t >= 64) {
        const float* eb = enc_Whh + g * H + p * 64;
        const float* db = dec_Whh + g * H + p * 64;
        #pragma unroll
        for (int i = 0; i < 16; ++i) {
            wE[i] = *(const float4*)(eb + 4 * i);
            wD[i] = *(const float4*)(db + 4 * i);
        }
        if (p == 0) { bhhE = enc_bhh[g]; bhhD = dec_bhh[g]; }
    }

    // fc_W in registers: primary row t>>2, chunk t&3; secondary 64+(t>>2) for t<40
    const int rF = t >> 2;
    float4 wF[16], wF2[16];
    {
        const float* fp = fc_W + rF * H + p * 64;
        #pragma unroll
        for (int i = 0; i < 16; ++i) wF[i] = *(const float4*)(fp + 4 * i);
        if (t < 40) {
            const float* fp2 = fc_W + (64 + rF) * H + p * 64;
            #pragma unroll
            for (int i = 0; i < 16; ++i) wF2[i] = *(const float4*)(fp2 + 4 * i);
        }
    }

    int tok = 2;  // BOS
    for (int s = 0; s <= L + STEPS; ++s) {      // 0..52
        // ---- wait for h^(s): thread t polls its own packed word ----
        {
            const unsigned long long* src = hx + (s & 1) * H + t;
            unsigned long long u = __hip_atomic_load(src, __ATOMIC_RELAXED,
                                                     __HIP_MEMORY_SCOPE_AGENT);
            while ((unsigned)u != (unsigned)s) {
                __builtin_amdgcn_s_sleep(1);
                u = __hip_atomic_load(src, __ATOMIC_RELAXED,
                                      __HIP_MEMORY_SCOPE_AGENT);
            }
            float hv = __uint_as_float((unsigned)(u >> 32));
            hl[t] = hv; hl[260 + t] = hv; hl[520 + t] = hv; hl[780 + t] = hv;
        }
        __syncthreads();

        const bool dec_out = (s >= L + 1);
        if (dec_out) {
            // ---- logits from registers (all 256 threads, conflict-free hl) ----
            const float* hb = hl + p * 324;
            float a = 0.f;
            #pragma unroll
            for (int i = 0; i < 16; ++i) {
                float4 h4 = *(const float4*)(hb + 4 * i);
                a = fmaf(wF[i].x, h4.x, fmaf(wF[i].y, h4.y,
                      fmaf(wF[i].z, h4.z, fmaf(wF[i].w, h4.w, a))));
            }
            a += __shfl_xor(a, 1); a += __shfl_xor(a, 2);
            if (p == 0) log_l[rF] = a + fb[rF];
            if (t < 40) {
                float a2 = 0.f;
                #pragma unroll
                for (int i = 0; i < 16; ++i) {
                    float4 h4 = *(const float4*)(hb + 4 * i);
                    a2 = fmaf(wF2[i].x, h4.x, fmaf(wF2[i].y, h4.y,
                           fmaf(wF2[i].z, h4.z, fmaf(wF2[i].w, h4.w, a2))));
                }
                a2 += __shfl_xor(a2, 1); a2 += __shfl_xor(a2, 2);
                if (p == 0) log_l[64 + rF] = a2 + fb[64 + rF];
            }
            __syncthreads();
        }

        // ---- wave0: argmax  ||  waves1-3: GRU matvec (tok-independent) ----
        if (t < 64) {
            if (dec_out) {
                float v = log_l[t]; int bi = t;
                if (t < VOUT - 64) {
                    float v2 = log_l[64 + t];
                    if (v2 > v) { v = v2; bi = 64 + t; }
                }
                #pragma unroll
                for (int mm = 1; mm < 64; mm <<= 1) {
                    float ov = __shfl_xor(v, mm);
                    int   ob = __shfl_xor(bi, mm);
                    if (ov > v || (ov == v && ob < bi)) { v = ov; bi = ob; }
                }
                if (t == 0) {
                    bool eos = (bi == 3);                    // EOS=3
                    if (w == 0 && !eos) out[s - (L + 1)] = bi;
                    s_tok = bi;
                    if (eos) s_done = 1;
                }
            }
        } else {
            float acc = (s < L) ? bhhE : bhhD;
            const float* hb = hl + p * 324;      // copy p, k-offset p*64
            if (s < L) {
                #pragma unroll
                for (int i = 0; i < 16; ++i) {
                    float4 h4 = *(const float4*)(hb + 4 * i);
                    acc = fmaf(wE[i].x, h4.x, fmaf(wE[i].y, h4.y,
                          fmaf(wE[i].z, h4.z, fmaf(wE[i].w, h4.w, acc))));
                }
            } else {
                #pragma unroll
                for (int i = 0; i < 16; ++i) {
                    float4 h4 = *(const float4*)(hb + 4 * i);
                    acc = fmaf(wD[i].x, h4.x, fmaf(wD[i].y, h4.y,
                          fmaf(wD[i].z, h4.z, fmaf(wD[i].w, h4.w, acc))));
                }
            }
            acc += __shfl_xor(acc, 1);
            acc += __shfl_xor(acc, 2);
            if (p == 0) gh_l[m >> 2] = acc;
        }
        __syncthreads();

        if (dec_out) {
            tok = s_tok;
            if (s_done || s == L + STEPS) break;
        }

        // ---- gates -> h^(s+1) slice: ONE packed 8B tagged store ----
        if (t < HW) {
            const float* gi = (s < L) ? (egi_l + s * ROWS) : (dgi_l + tok * ROWS);
            float r = sigmoidf_(gi[t]      + gh_l[t]);
            float z = sigmoidf_(gi[16 + t] + gh_l[16 + t]);
            float n = tanhf    (gi[32 + t] + r * gh_l[32 + t]);
            float hn = (1.f - z) * n + z * hl[w * HW + t];
            unsigned long long pk =
                ((unsigned long long)__float_as_uint(hn) << 32) |
                (unsigned)(s + 1);
            __hip_atomic_store(hx + ((s + 1) & 1) * H + w * HW + t, pk,
                               __ATOMIC_RELAXED, __HIP_MEMORY_SCOPE_AGENT);
        }
        // no trailing barrier: cross-WG ordering rides on the tagged word;
        // intra-WG LDS hazards are covered by the per-iteration barriers.
    }
}

extern "C" void kernel_launch(void* const* d_in, const int* in_sizes, int n_in,
                              void* d_out, int out_size, void* d_ws, size_t ws_size,
                              hipStream_t stream) {
    const int*   enc_input = (const int*)  d_in[0];
    const float* enc_emb   = (const float*)d_in[1];
    const float* enc_Wih   = (const float*)d_in[2];
    const float* enc_Whh   = (const float*)d_in[3];
    const float* enc_bih   = (const float*)d_in[4];
    const float* enc_bhh   = (const float*)d_in[5];
    const float* dec_emb   = (const float*)d_in[6];
    const float* dec_Wih   = (const float*)d_in[7];
    const float* dec_Whh   = (const float*)d_in[8];
    const float* dec_bih   = (const float*)d_in[9];
    const float* dec_bhh   = (const float*)d_in[10];
    const float* fc_W      = (const float*)d_in[11];
    const float* fc_b      = (const float*)d_in[12];
    float* ws  = (float*)d_ws;
    int*  outp = (int*)d_out;

    hipLaunchKernelGGL(prep, dim3((NITEMS * H3 + 3) / 4), dim3(256), 0, stream,
                       enc_input, enc_emb, enc_Wih, enc_bih,
                       dec_emb, dec_Wih, dec_bih, ws);
    hipLaunchKernelGGL(gru_seq, dim3(NB), dim3(256), 0, stream,
                       enc_Whh, enc_bhh, dec_Whh, dec_bhh, fc_W, fc_b,
                       ws, outp);
}